// Round 4
// baseline (162.268 us; speedup 1.0000x reference)
//
#include <hip/hip_runtime.h>
#include <math.h>

#define L 64
#define D 512
#define E 8
#define F 256
#define NEG_INF -1e30f
#define RPB 8     // rows per block in row_kernel

// Raw barrier that does NOT drain vmcnt: LDS ordering only. Prefetch global
// loads stay in flight across it (the T3/T4 counted-wait principle).
#define BAR() do { asm volatile("s_waitcnt lgkmcnt(0)" ::: "memory"); \
                   __builtin_amdgcn_s_barrier();                      \
                   asm volatile("" ::: "memory"); } while (0)

// ---------- proj stage A: partial over 16-wide o-chunks (grid: E*32, 512 thr) ----------
__global__ void projA_kernel(const float* __restrict__ Wk, const float* __restrict__ q,
                             float* __restrict__ part) {
    const int e = blockIdx.x >> 5, oc = blockIdx.x & 31;
    const int d = threadIdx.x;
    const float* wb = Wk + ((size_t)e * D + oc * 16) * D + d;
    const float* qb = q + e * D + oc * 16;
    float acc = 0.f;
    #pragma unroll
    for (int o = 0; o < 16; ++o) acc += wb[(size_t)o * D] * qb[o];
    part[(size_t)blockIdx.x * D + d] = acc;
}

// ---------- prep2: fused proj-combine (blocks 0..7) + trans_W transpose (8..263) ----------
__global__ void prep2_kernel(const float* __restrict__ part, const float* __restrict__ W,
                             float* __restrict__ proj, float* __restrict__ wT) {
    const int b = blockIdx.x;
    if (b < 8) {
        const int i = b * 512 + threadIdx.x;      // i = e*D + d, 0..E*D-1
        const int e = i >> 9, d = i & (D - 1);
        float s = 0.f;
        #pragma unroll
        for (int oc = 0; oc < 32; ++oc) s += part[(size_t)(e * 32 + oc) * D + d];
        proj[i] = s;
    } else {
        const int i = (b - 8) * 512 + threadIdx.x;   // 0..D*F-1
        const int f = i & (F - 1), d = i >> 8;
        wT[(size_t)d * F + f] = W[(size_t)f * D + d];
    }
}

// ---------- row_kernel: 256 persistent blocks x 8 rows, pipelined gather ----------
// One body phase list: A prefetch-next -> B mean -> C gate partials -> D top2 ->
// E score dots -> F softmax -> H pooled. Raw barriers keep prefetch in flight.
#define BODY(C0, C1, MC, N0, N1, MN, ROW, PRE)                                      \
  {                                                                                 \
    if (PRE) {                                                                      \
      const int* sp = sample + ((ROW) + 1) * L + wv * 8;                            \
      _Pragma("unroll")                                                             \
      for (int j = 0; j < 8; ++j) {                                                 \
        int ix = sp[j];                                                             \
        MN[j] = (ix != 0) ? 1.f : 0.f;                                              \
        const float4* src = (const float4*)(emb_table + (size_t)ix * D);            \
        N0[j] = src[lane]; N1[j] = src[lane + 64];                                  \
      }                                                                             \
    }                                                                               \
    { /* B: masked mean partials from cur regs */                                   \
      float4 s0 = {0,0,0,0}, s1 = {0,0,0,0};                                        \
      _Pragma("unroll")                                                             \
      for (int j = 0; j < 8; ++j) {                                                 \
        float m = MC[j];                                                            \
        s0.x += m*C0[j].x; s0.y += m*C0[j].y; s0.z += m*C0[j].z; s0.w += m*C0[j].w; \
        s1.x += m*C1[j].x; s1.y += m*C1[j].y; s1.z += m*C1[j].z; s1.w += m*C1[j].w; \
      }                                                                             \
      ((float4*)red[wv])[lane] = s0; ((float4*)red[wv])[lane + 64] = s1;            \
    }                                                                               \
    BAR();                                                                          \
    { /* C: gate partial scores per wave */                                         \
      float g = 0.f;                                                                \
      _Pragma("unroll")                                                             \
      for (int w = 0; w < 8; ++w) g += red[w][tid];                                 \
      g *= (1.f / 64.f);                                                            \
      _Pragma("unroll")                                                             \
      for (int e = 0; e < E; ++e) {                                                 \
        float v = g * gate_W[e * D + tid];                                          \
        _Pragma("unroll")                                                           \
        for (int off = 32; off; off >>= 1) v += __shfl_xor(v, off, 64);             \
        if (lane == 0) gred[wv][e] = v;                                             \
      }                                                                             \
      if (lane == 0) {                                                              \
        float c = 0.f;                                                              \
        _Pragma("unroll")                                                           \
        for (int j = 0; j < 8; ++j) c += MC[j];                                     \
        gred[wv][E] = c;                                                            \
      }                                                                             \
    }                                                                               \
    BAR();                                                                          \
    if (tid == 0) { /* D: gate finish + top2 + allpad, single thread */             \
      float gs[E]; float cnt = 0.f;                                                 \
      _Pragma("unroll")                                                             \
      for (int e = 0; e < E; ++e) {                                                 \
        float s = gate_b[e];                                                        \
        _Pragma("unroll")                                                           \
        for (int w = 0; w < 8; ++w) s += gred[w][e];                                \
        gs[e] = s;                                                                  \
      }                                                                             \
      _Pragma("unroll")                                                             \
      for (int w = 0; w < 8; ++w) cnt += gred[w][E];                                \
      int b0 = 0; float v0 = gs[0];                                                 \
      for (int e = 1; e < E; ++e) if (gs[e] > v0) { v0 = gs[e]; b0 = e; }           \
      int b1 = -1; float v1 = -3.4e38f;                                             \
      for (int e = 0; e < E; ++e) if (e != b0 && gs[e] > v1) { v1 = gs[e]; b1 = e; }\
      float ex = expf(v1 - v0); float inv = 1.f / (1.f + ex);                       \
      wsel[0] = inv; wsel[1] = ex * inv;                                            \
      esel[0] = b0; esel[1] = b1;                                                   \
      allpad = (cnt == 0.f) ? 1 : 0;                                                \
    }                                                                               \
    BAR();                                                                          \
    { /* E: score dots for the two selected experts */                              \
      const float4* pe0 = (const float4*)(proj + esel[0] * D);                      \
      const float4* pe1 = (const float4*)(proj + esel[1] * D);                      \
      float4 b00 = pe0[lane], b01 = pe0[lane + 64];                                 \
      float4 b10 = pe1[lane], b11 = pe1[lane + 64];                                 \
      _Pragma("unroll")                                                             \
      for (int j = 0; j < 8; ++j) {                                                 \
        float s0 = C0[j].x*b00.x + C0[j].y*b00.y + C0[j].z*b00.z + C0[j].w*b00.w    \
                 + C1[j].x*b01.x + C1[j].y*b01.y + C1[j].z*b01.z + C1[j].w*b01.w;   \
        float s1 = C0[j].x*b10.x + C0[j].y*b10.y + C0[j].z*b10.z + C0[j].w*b10.w    \
                 + C1[j].x*b11.x + C1[j].y*b11.y + C1[j].z*b11.z + C1[j].w*b11.w;   \
        _Pragma("unroll")                                                           \
        for (int off = 32; off; off >>= 1) {                                        \
          s0 += __shfl_xor(s0, off, 64); s1 += __shfl_xor(s1, off, 64);             \
        }                                                                           \
        if (lane == 0) {                                                            \
          scr[0][wv * 8 + j] = (MC[j] != 0.f) ? s0 : NEG_INF;                       \
          scr[1][wv * 8 + j] = (MC[j] != 0.f) ? s1 : NEG_INF;                       \
        }                                                                           \
      }                                                                             \
    }                                                                               \
    BAR();                                                                          \
    if (tid < 128) { /* F: masked softmax over L, waves 0 and 1 */                  \
      float s = scr[wv][lane];                                                      \
      float m = s;                                                                  \
      _Pragma("unroll")                                                             \
      for (int off = 32; off; off >>= 1) m = fmaxf(m, __shfl_xor(m, off, 64));      \
      float pex = expf(s - m);                                                      \
      float su = pex;                                                               \
      _Pragma("unroll")                                                             \
      for (int off = 32; off; off >>= 1) su += __shfl_xor(su, off, 64);             \
      att2[wv][lane] = pex / su;                                                    \
    }                                                                               \
    BAR();                                                                          \
    { /* H: pooled partials (cf recomputed per lane from att2 broadcasts) */        \
      float w0 = wsel[0], w1 = wsel[1];                                             \
      float4 s0 = {0,0,0,0}, s1 = {0,0,0,0};                                        \
      _Pragma("unroll")                                                             \
      for (int j = 0; j < 8; ++j) {                                                 \
        float c = w0 * att2[0][wv * 8 + j] + w1 * att2[1][wv * 8 + j];              \
        s0.x += c*C0[j].x; s0.y += c*C0[j].y; s0.z += c*C0[j].z; s0.w += c*C0[j].w; \
        s1.x += c*C1[j].x; s1.y += c*C1[j].y; s1.z += c*C1[j].z; s1.w += c*C1[j].w; \
      }                                                                             \
      ((float4*)red[wv])[lane] = s0; ((float4*)red[wv])[lane + 64] = s1;            \
    }                                                                               \
    BAR();                                                                          \
    {                                                                               \
      float acc = 0.f;                                                              \
      _Pragma("unroll")                                                             \
      for (int w = 0; w < 8; ++w) acc += red[w][tid];                               \
      if (allpad) acc = 0.f;                                                        \
      pooled[(size_t)(ROW) * D + tid] = acc;                                        \
    }                                                                               \
    BAR();                                                                          \
  }

__launch_bounds__(512, 2)   // 256-VGPR cap: fits double-buffered 128-reg emb + working set
__global__ void row_kernel(const int* __restrict__ sample,
                           const float* __restrict__ emb_table,
                           const float* __restrict__ proj,
                           const float* __restrict__ gate_W,
                           const float* __restrict__ gate_b,
                           float* __restrict__ pooled) {
    __shared__ float red[8][D];        // 16 KiB
    __shared__ float gred[8][E + 2];
    __shared__ float scr[2][L];
    __shared__ float att2[2][L];
    __shared__ float wsel[2];
    __shared__ int   esel[2];
    __shared__ int   allpad;

    const int tid  = threadIdx.x;
    const int lane = tid & 63;
    const int wv   = tid >> 6;
    const int base = blockIdx.x * RPB;

    float4 A0[8], A1[8], B0[8], B1[8];
    float  ma[8], mb[8];

    // prologue: gather row `base` into A
    {
        const int* sp = sample + base * L + wv * 8;
        #pragma unroll
        for (int j = 0; j < 8; ++j) {
            int ix = sp[j];
            ma[j] = (ix != 0) ? 1.f : 0.f;
            const float4* src = (const float4*)(emb_table + (size_t)ix * D);
            A0[j] = src[lane]; A1[j] = src[lane + 64];
        }
    }

    #pragma unroll 1
    for (int i = 0; i < RPB; i += 2) {
        BODY(A0, A1, ma, B0, B1, mb, base + i,     (i + 1 < RPB));
        BODY(B0, B1, mb, A0, A1, ma, base + i + 1, (i + 2 < RPB));
    }
}

// ---------- out_kernel: gelu(pooled @ wT + b); 4 rows/wave to cut wT L2 traffic ----------
__launch_bounds__(256, 4)
__global__ void out_kernel(const float* __restrict__ pooled,
                           const float* __restrict__ wT,     // [D][F]
                           const float* __restrict__ trans_b,
                           float* __restrict__ out) {
    __shared__ float pl[16 * D];            // 32 KiB
    const int tid = threadIdx.x, lane = tid & 63, w = tid >> 6;
    const int n0 = blockIdx.x * 16;

    {
        const float4* src = (const float4*)(pooled + (size_t)n0 * D);
        float4* dst = (float4*)pl;
        #pragma unroll
        for (int i = 0; i < 8; ++i) dst[tid + 256 * i] = src[tid + 256 * i];
    }
    __syncthreads();

    const float* p0 = pl + (w * 4) * D;     // this wave's 4 rows
    const float4* wT4 = (const float4*)wT;
    float4 a0 = {0,0,0,0}, a1 = {0,0,0,0}, a2 = {0,0,0,0}, a3 = {0,0,0,0};
    #pragma unroll 8
    for (int d4 = 0; d4 < D / 4; ++d4) {
        float4 q0 = *(const float4*)&p0[d4 * 4];
        float4 q1 = *(const float4*)&p0[D + d4 * 4];
        float4 q2 = *(const float4*)&p0[2 * D + d4 * 4];
        float4 q3 = *(const float4*)&p0[3 * D + d4 * 4];
        #pragma unroll
        for (int t = 0; t < 4; ++t) {
            float4 wt = wT4[(d4 * 4 + t) * 64 + lane];
            float e0 = (t == 0) ? q0.x : (t == 1) ? q0.y : (t == 2) ? q0.z : q0.w;
            float e1 = (t == 0) ? q1.x : (t == 1) ? q1.y : (t == 2) ? q1.z : q1.w;
            float e2 = (t == 0) ? q2.x : (t == 1) ? q2.y : (t == 2) ? q2.z : q2.w;
            float e3 = (t == 0) ? q3.x : (t == 1) ? q3.y : (t == 2) ? q3.z : q3.w;
            a0.x += e0*wt.x; a0.y += e0*wt.y; a0.z += e0*wt.z; a0.w += e0*wt.w;
            a1.x += e1*wt.x; a1.y += e1*wt.y; a1.z += e1*wt.z; a1.w += e1*wt.w;
            a2.x += e2*wt.x; a2.y += e2*wt.y; a2.z += e2*wt.z; a2.w += e2*wt.w;
            a3.x += e3*wt.x; a3.y += e3*wt.y; a3.z += e3*wt.z; a3.w += e3*wt.w;
        }
    }

    float4 b4 = ((const float4*)trans_b)[lane];
    #define GELU(v) (0.5f * (v) * (1.f + erff((v) * 0.70710678118654752f)))
    float4 o;
    o.x = GELU(a0.x + b4.x); o.y = GELU(a0.y + b4.y); o.z = GELU(a0.z + b4.z); o.w = GELU(a0.w + b4.w);
    ((float4*)(out + (size_t)(n0 + w * 4 + 0) * F))[lane] = o;
    o.x = GELU(a1.x + b4.x); o.y = GELU(a1.y + b4.y); o.z = GELU(a1.z + b4.z); o.w = GELU(a1.w + b4.w);
    ((float4*)(out + (size_t)(n0 + w * 4 + 1) * F))[lane] = o;
    o.x = GELU(a2.x + b4.x); o.y = GELU(a2.y + b4.y); o.z = GELU(a2.z + b4.z); o.w = GELU(a2.w + b4.w);
    ((float4*)(out + (size_t)(n0 + w * 4 + 2) * F))[lane] = o;
    o.x = GELU(a3.x + b4.x); o.y = GELU(a3.y + b4.y); o.z = GELU(a3.z + b4.z); o.w = GELU(a3.w + b4.w);
    ((float4*)(out + (size_t)(n0 + w * 4 + 3) * F))[lane] = o;
    #undef GELU
}

extern "C" void kernel_launch(void* const* d_in, const int* in_sizes, int n_in,
                              void* d_out, int out_size, void* d_ws, size_t ws_size,
                              hipStream_t stream) {
    const int*   sample    = (const int*)d_in[0];
    const float* emb_table = (const float*)d_in[1];
    const float* expert_q  = (const float*)d_in[2];
    const float* expert_Wk = (const float*)d_in[3];
    const float* gate_W    = (const float*)d_in[4];
    const float* gate_b    = (const float*)d_in[5];
    const float* trans_W   = (const float*)d_in[6];
    const float* trans_b   = (const float*)d_in[7];
    float* out = (float*)d_out;

    const int N = in_sizes[0] / L;                 // B*T = 2048

    float* proj   = (float*)d_ws;                  // E*D
    float* pooled = proj + E * D;                  // N*D
    float* part   = pooled + (size_t)N * D;        // E*32*D
    float* wT     = part + E * 32 * D;             // D*F
    (void)ws_size; (void)n_in; (void)out_size;

    projA_kernel<<<E * 32, D, 0, stream>>>(expert_Wk, expert_q, part);
    prep2_kernel<<<8 + (D * F) / 512, 512, 0, stream>>>(part, trans_W, proj, wT);
    row_kernel<<<N / RPB, 512, 0, stream>>>(sample, emb_table, proj, gate_W, gate_b, pooled);
    out_kernel<<<N / 16, 256, 0, stream>>>(pooled, wT, trans_b, out);
}